// Round 1
// baseline (678.261 us; speedup 1.0000x reference)
//
#include <hip/hip_runtime.h>

// Problem constants: B=4, C=64, H=W=64, HW=4096, P=64, Q=3 (CQ=192)
namespace {
constexpr int IMG  = 262144;     // 64*4096 floats per batch image
constexpr int MS   = 2;          // m-split for attention parallelism
// workspace float offsets
constexpr int TOPO = 0;          // top   [b][p][m]      1048576
constexpr int CENO = 1048576;    // center[b][p][n]      1048576
constexpr int BOTO = 2097152;    // bottom[b][m][c]      1048576
constexpr int PVO  = 3145728;    // pv    [s][b][n][c]   2*1048576
constexpr int MSO  = 5242880;    // m_s   [s][b][strip]  512
constexpr int ZSO  = 5243392;    // z_s                  512
constexpr int MO_  = 5243904;    // M[b]                 4
constexpr int ZO_  = 5243908;    // Z[b]                 4
constexpr int UO   = 5243912;    // u     [b][c][h][w]   1048576
constexpr int WTBO = 6292488;    // bottom_w reordered   110592
constexpr int WTOO = 6403080;    // out_w reordered      110592
// total = 6513672 floats = ~24.9 MB
}

// Reorder 3x3 weights: w[o][(p*64+ci)*9+tap] -> wT[ci][p*9+tap][o]
__global__ void k_reorder(const float* bw, const float* ow, float* ws) {
    int idx = blockIdx.x * 256 + threadIdx.x;
    if (idx >= 2 * 110592) return;
    int tsel = idx / 110592;
    int r    = idx - tsel * 110592;
    int ci   = r / 1728;
    int rr   = r - ci * 1728;
    int k27  = rr >> 6;
    int o    = rr & 63;
    int p    = k27 / 9, tap = k27 - p * 9;
    const float* src = tsel ? ow : bw;
    ws[(tsel ? WTOO : WTBO) + r] = src[o * 1728 + (p * 64 + ci) * 9 + tap];
}

// Fused top+center 1x1 SelfONN convs as GEMM. grid 512 = 256 n-tiles x 2 convs.
__global__ __launch_bounds__(256) void k_conv1(const float* __restrict__ x,
                                               const float* __restrict__ tw, const float* __restrict__ tb,
                                               const float* __restrict__ cw, const float* __restrict__ cb,
                                               float* __restrict__ ws) {
    __shared__ float xt[4096];        // [ci][n] raw x tile
    __shared__ float wtc[64 * 68];    // [ci][o] weight chunk (one power), padded
    int t  = threadIdx.x;
    int bx = blockIdx.x;
    int nt = bx & 255, ot = bx >> 8;
    int b  = nt >> 6, n0 = (nt & 63) << 6;
    const float* w    = ot ? cw : tw;
    const float* bias = ot ? cb : tb;
    float* dst = ws + (ot ? CENO : TOPO) + b * IMG;
    int tx = t & 15, ty = t >> 4;

    for (int i = t; i < 4096; i += 256) {
        int ci = i >> 6, n = i & 63;
        xt[i] = x[b * IMG + ci * 4096 + n0 + n];
    }
    float acc[4][4] = {};
    #pragma unroll
    for (int p = 0; p < 3; ++p) {
        __syncthreads();
        for (int i = t; i < 4096; i += 256) {
            int o = i >> 6, cc = i & 63;
            wtc[cc * 68 + o] = w[o * 192 + p * 64 + cc];
        }
        __syncthreads();
        #pragma unroll 4
        for (int ci = 0; ci < 64; ++ci) {
            float4 a = *(float4*)&wtc[ci * 68 + ty * 4];
            float4 v = *(float4*)&xt[ci * 64 + tx * 4];
            float vx = v.x, vy = v.y, vz = v.z, vw = v.w;
            if (p == 1) { vx *= vx; vy *= vy; vz *= vz; vw *= vw; }
            if (p == 2) { vx = vx * vx * vx; vy = vy * vy * vy; vz = vz * vz * vz; vw = vw * vw * vw; }
            acc[0][0] += a.x * vx; acc[0][1] += a.x * vy; acc[0][2] += a.x * vz; acc[0][3] += a.x * vw;
            acc[1][0] += a.y * vx; acc[1][1] += a.y * vy; acc[1][2] += a.y * vz; acc[1][3] += a.y * vw;
            acc[2][0] += a.z * vx; acc[2][1] += a.z * vy; acc[2][2] += a.z * vz; acc[2][3] += a.z * vw;
            acc[3][0] += a.w * vx; acc[3][1] += a.w * vy; acc[3][2] += a.w * vz; acc[3][3] += a.w * vw;
        }
    }
    #pragma unroll
    for (int i = 0; i < 4; ++i) {
        int o = ty * 4 + i;
        float bv = bias[o];
        float4 r = make_float4(acc[i][0] + bv, acc[i][1] + bv, acc[i][2] + bv, acc[i][3] + bv);
        *(float4*)&dst[o * 4096 + n0 + tx * 4] = r;
    }
}

// 3x3 SelfONN conv, implicit GEMM over (ci, power, tap). One block per (b, output row).
// layoutPix=1 -> dst[b][m][c] (pixel-major), else dst[b][o][h][w].
__global__ __launch_bounds__(512) void k_conv3(const float* __restrict__ src,
                                               const float* __restrict__ wt,
                                               const float* __restrict__ bias,
                                               float* __restrict__ dst, int layoutPix) {
    __shared__ float xp[3 * 198];   // [p][kh][cc 0..65], cc = iw+1
    __shared__ float wtile[1728];   // [k27][o]
    int t  = threadIdx.x;
    int bx = blockIdx.x;
    int b  = bx >> 6, h = bx & 63;
    int tx = t & 15, ty = t >> 4;     // cols 4tx..+3, o pair 2ty..+1
    int w0 = tx * 4, o0 = ty * 2;
    float acc[4][2] = {};

    for (int ci = 0; ci < 64; ++ci) {
        __syncthreads();
        if (t < 198) {
            int rr = t / 66, cc = t - rr * 66;
            int ih = h + rr - 1, iw = cc - 1;
            float xv = 0.f;
            if (ih >= 0 && ih < 64 && iw >= 0 && iw < 64)
                xv = src[b * IMG + ci * 4096 + ih * 64 + iw];
            xp[rr * 66 + cc]       = xv;
            xp[198 + rr * 66 + cc] = xv * xv;
            xp[396 + rr * 66 + cc] = xv * xv * xv;
        }
        for (int i = t; i < 1728; i += 512)
            wtile[i] = wt[ci * 1728 + i];
        __syncthreads();
        #pragma unroll
        for (int p = 0; p < 3; ++p) {
            #pragma unroll
            for (int kh = 0; kh < 3; ++kh) {
                float xv[6];
                #pragma unroll
                for (int q = 0; q < 6; ++q) xv[q] = xp[p * 198 + kh * 66 + w0 + q];
                #pragma unroll
                for (int kw = 0; kw < 3; ++kw) {
                    int k27 = p * 9 + kh * 3 + kw;
                    float2 wv = *(float2*)&wtile[k27 * 64 + o0];
                    #pragma unroll
                    for (int j = 0; j < 4; ++j) {
                        acc[j][0] += wv.x * xv[j + kw];
                        acc[j][1] += wv.y * xv[j + kw];
                    }
                }
            }
        }
    }
    if (layoutPix) {
        #pragma unroll
        for (int j = 0; j < 4; ++j)
            #pragma unroll
            for (int i2 = 0; i2 < 2; ++i2)
                dst[b * IMG + (h * 64 + w0 + j) * 64 + o0 + i2] = acc[j][i2] + bias[o0 + i2];
    } else {
        #pragma unroll
        for (int i2 = 0; i2 < 2; ++i2) {
            int o = o0 + i2;
            float bv = bias[o];
            float4 r = make_float4(acc[0][i2] + bv, acc[1][i2] + bv, acc[2][i2] + bv, acc[3][i2] + bv);
            *(float4*)&dst[b * IMG + o * 4096 + h * 64 + w0] = r;
        }
    }
}

// Flash-style global-softmax attention. grid 512: (strip 64) x (b 4) x (split 2).
// Block: 64-row strip, iterates 32 m-tiles of 64; scalar online max/Z (global softmax).
__global__ __launch_bounds__(256, 2) void k_attn(float* __restrict__ ws) {
    __shared__ float cs[4096];        // center [p][n]
    __shared__ float tps[64 * 68];    // top tile [p][m] -> reused as exp(S) [m][n] (swizzled)
    __shared__ float bs[4096];        // bottom tile [m][c]
    __shared__ float red[4];
    int t  = threadIdx.x, tx = t & 15, ty = t >> 4;
    int bx = blockIdx.x;
    int st = bx & 63, b = (bx >> 6) & 3, s = bx >> 8;
    int n0 = st * 64;
    const float* top = ws + TOPO + b * IMG;
    const float* cen = ws + CENO + b * IMG;
    const float* bot = ws + BOTO + b * IMG;

    for (int i = t; i < 1024; i += 256) {
        int p = i >> 4, q = i & 15;
        *(float4*)&cs[p * 64 + q * 4] = *(const float4*)&cen[p * 4096 + n0 + q * 4];
    }
    float pv[4][4] = {};
    float runm = -3.0e38f, zacc = 0.f;

    for (int tt = 0; tt < 32; ++tt) {
        int m0 = s * 2048 + tt * 64;
        __syncthreads();   // prev PV reads done; safe to restage
        for (int i = t; i < 1024; i += 256) {
            int p = i >> 4, q = i & 15;
            *(float4*)&tps[p * 68 + q * 4] = *(const float4*)&top[p * 4096 + m0 + q * 4];
            *(float4*)&bs[p * 64 + q * 4]  = *(const float4*)&bot[(m0 + p) * 64 + q * 4];
        }
        __syncthreads();
        float s_[4][4];
        #pragma unroll
        for (int i = 0; i < 4; ++i)
            #pragma unroll
            for (int j = 0; j < 4; ++j) s_[i][j] = 0.f;
        #pragma unroll 4
        for (int k = 0; k < 64; ++k) {
            float4 a  = *(float4*)&cs[k * 64 + ty * 4];
            float4 bb = *(float4*)&tps[k * 68 + tx * 4];
            s_[0][0] += a.x * bb.x; s_[0][1] += a.x * bb.y; s_[0][2] += a.x * bb.z; s_[0][3] += a.x * bb.w;
            s_[1][0] += a.y * bb.x; s_[1][1] += a.y * bb.y; s_[1][2] += a.y * bb.z; s_[1][3] += a.y * bb.w;
            s_[2][0] += a.z * bb.x; s_[2][1] += a.z * bb.y; s_[2][2] += a.z * bb.z; s_[2][3] += a.z * bb.w;
            s_[3][0] += a.w * bb.x; s_[3][1] += a.w * bb.y; s_[3][2] += a.w * bb.z; s_[3][3] += a.w * bb.w;
        }
        float tm = s_[0][0];
        #pragma unroll
        for (int i = 0; i < 4; ++i)
            #pragma unroll
            for (int j = 0; j < 4; ++j) tm = fmaxf(tm, s_[i][j]);
        for (int off = 32; off; off >>= 1) tm = fmaxf(tm, __shfl_xor(tm, off, 64));
        if ((t & 63) == 0) red[t >> 6] = tm;
        __syncthreads();   // also: everyone done reading tps as top-tile
        float tmax = fmaxf(fmaxf(red[0], red[1]), fmaxf(red[2], red[3]));
        float newm = fmaxf(runm, tmax);
        float sc = __expf(runm - newm);
        zacc *= sc;
        #pragma unroll
        for (int i = 0; i < 4; ++i)
            #pragma unroll
            for (int j = 0; j < 4; ++j) pv[i][j] *= sc;
        #pragma unroll
        for (int j = 0; j < 4; ++j) {
            float e0 = __expf(s_[0][j] - newm);
            float e1 = __expf(s_[1][j] - newm);
            float e2 = __expf(s_[2][j] - newm);
            float e3 = __expf(s_[3][j] - newm);
            zacc += (e0 + e1) + (e2 + e3);
            float4 v = make_float4(e0, e1, e2, e3);
            *(float4*)&tps[(tx * 4 + j) * 68 + (((ty + tx) & 15) * 4)] = v;   // [m][n], swizzled
        }
        runm = newm;
        __syncthreads();
        #pragma unroll 4
        for (int m = 0; m < 64; ++m) {
            float4 a  = *(float4*)&tps[m * 68 + (((ty + (m >> 2)) & 15) * 4)];
            float4 bb = *(float4*)&bs[m * 64 + tx * 4];
            pv[0][0] += a.x * bb.x; pv[0][1] += a.x * bb.y; pv[0][2] += a.x * bb.z; pv[0][3] += a.x * bb.w;
            pv[1][0] += a.y * bb.x; pv[1][1] += a.y * bb.y; pv[1][2] += a.y * bb.z; pv[1][3] += a.y * bb.w;
            pv[2][0] += a.z * bb.x; pv[2][1] += a.z * bb.y; pv[2][2] += a.z * bb.z; pv[2][3] += a.z * bb.w;
            pv[3][0] += a.w * bb.x; pv[3][1] += a.w * bb.y; pv[3][2] += a.w * bb.z; pv[3][3] += a.w * bb.w;
        }
    }
    __syncthreads();
    float zz = zacc;
    for (int off = 32; off; off >>= 1) zz += __shfl_xor(zz, off, 64);
    if ((t & 63) == 0) red[t >> 6] = zz;
    __syncthreads();
    if (t == 0) {
        ws[MSO + s * 256 + b * 64 + st] = runm;
        ws[ZSO + s * 256 + b * 64 + st] = red[0] + red[1] + red[2] + red[3];
    }
    float* pvp = ws + PVO + s * 1048576 + b * IMG;
    #pragma unroll
    for (int i = 0; i < 4; ++i) {
        float4 r = make_float4(pv[i][0], pv[i][1], pv[i][2], pv[i][3]);
        *(float4*)&pvp[(n0 + ty * 4 + i) * 64 + tx * 4] = r;
    }
}

// Combine per-block (m_s, Z_s) -> global M, Z per batch.
__global__ __launch_bounds__(128) void k_mz(float* __restrict__ ws) {
    int b = blockIdx.x, t = threadIdx.x;
    int s = t >> 6, st = t & 63;
    float m0 = ws[MSO + s * 256 + b * 64 + st];
    float z0 = ws[ZSO + s * 256 + b * 64 + st];
    float m = m0;
    for (int off = 32; off; off >>= 1) m = fmaxf(m, __shfl_xor(m, off, 64));
    __shared__ float rm[2], rz[2];
    if ((t & 63) == 0) rm[t >> 6] = m;
    __syncthreads();
    float M = fmaxf(rm[0], rm[1]);
    float z = z0 * __expf(m0 - M);
    for (int off = 32; off; off >>= 1) z += __shfl_xor(z, off, 64);
    if ((t & 63) == 0) rz[t >> 6] = z;
    __syncthreads();
    if (t == 0) { ws[MO_ + b] = M; ws[ZO_ + b] = rz[0] + rz[1]; }
}

// u = x + softmax(sp) @ bottom (flat reinterpretation handles the reshape quirk)
__global__ __launch_bounds__(256) void k_finalu(const float* __restrict__ x, float* __restrict__ ws) {
    int idx = blockIdx.x * 256 + threadIdx.x;   // < 1048576
    int b = idx >> 18;
    int rem = idx & 262143;
    int stp = (rem >> 6) >> 6;
    float M = ws[MO_ + b], Z = ws[ZO_ + b];
    float acc = 0.f;
    #pragma unroll
    for (int s = 0; s < MS; ++s) {
        float scl = __expf(ws[MSO + s * 256 + b * 64 + stp] - M);
        acc += ws[PVO + s * 1048576 + b * IMG + rem] * scl;
    }
    ws[UO + idx] = x[idx] + acc / Z;
}

extern "C" void kernel_launch(void* const* d_in, const int* in_sizes, int n_in,
                              void* d_out, int out_size, void* d_ws, size_t ws_size,
                              hipStream_t stream) {
    (void)in_sizes; (void)n_in; (void)out_size; (void)ws_size;
    const float* x  = (const float*)d_in[0];
    const float* tw = (const float*)d_in[1];
    const float* tb = (const float*)d_in[2];
    const float* cw = (const float*)d_in[3];
    const float* cb = (const float*)d_in[4];
    const float* bw = (const float*)d_in[5];
    const float* bb = (const float*)d_in[6];
    const float* ow = (const float*)d_in[7];
    const float* ob = (const float*)d_in[8];
    float* ws  = (float*)d_ws;
    float* out = (float*)d_out;

    hipLaunchKernelGGL(k_reorder, dim3(864), dim3(256), 0, stream, bw, ow, ws);
    hipLaunchKernelGGL(k_conv1, dim3(512), dim3(256), 0, stream, x, tw, tb, cw, cb, ws);
    hipLaunchKernelGGL(k_conv3, dim3(256), dim3(512), 0, stream, x, ws + WTBO, bb, ws + BOTO, 1);
    hipLaunchKernelGGL(k_attn, dim3(512), dim3(256), 0, stream, ws);
    hipLaunchKernelGGL(k_mz, dim3(4), dim3(128), 0, stream, ws);
    hipLaunchKernelGGL(k_finalu, dim3(4096), dim3(256), 0, stream, x, ws);
    hipLaunchKernelGGL(k_conv3, dim3(256), dim3(512), 0, stream, ws + UO, ws + WTOO, ob, out, 0);
}

// Round 2
// 492.797 us; speedup vs baseline: 1.3763x; 1.3763x over previous
//
#include <hip/hip_runtime.h>
#include <hip/hip_bf16.h>

// Problem constants: B=4, C=64, H=W=64, HW=4096, P=64, Q=3 (CQ=192)
namespace {
constexpr int IMG   = 262144;    // 64*4096 floats per batch image
constexpr int MS    = 4;         // m-split for attention parallelism
// workspace float offsets
constexpr int TOPO  = 0;         // bf16 topT [b][m 4096][p 64]   (524288 f) -- aliased by U after attn
constexpr int CENO  = 524288;    // bf16 cenT [b][n 4096][p 64]   (524288 f)
constexpr int BOTO  = 1048576;   // bf16 bot  [b][c 64][m 4096]   (524288 f)
constexpr int PVO   = 1572864;   // fp32 pv   [s 4][b][n][c]      (4194304 f)
constexpr int MSO   = 5767168;   // m_s [s 4][b 4][strip 32]      (512)
constexpr int ZSO   = 5767680;   // z_s                           (512)
constexpr int MO_   = 5768192;   // M[b] (4)
constexpr int ZO_   = 5768196;   // Z[b] (4)
constexpr int WTBO  = 5768200;   // bottom_w reordered fp32       (110592)
constexpr int WTOO  = 5878792;   // out_w reordered fp32          (110592)
constexpr int UO    = 0;         // fp32 u [b][c][h][w] -- aliases TOPO+CENO (dead after attn)
// total = 5989384 floats = ~24.0 MB
}

typedef __attribute__((ext_vector_type(8))) short short8v;   // 8 bf16 (4 VGPRs)
typedef __attribute__((ext_vector_type(4))) float f32x4;     // MFMA C/D frag

__device__ __forceinline__ short f2bf(float f) {
    __hip_bfloat16 h = __float2bfloat16(f);
    return *reinterpret_cast<short*>(&h);
}

// Reorder 3x3 weights: w[o][(p*64+ci)*9+tap] -> wT[ci][p*9+tap][o]
__global__ void k_reorder(const float* bw, const float* ow, float* ws) {
    int idx = blockIdx.x * 256 + threadIdx.x;
    if (idx >= 2 * 110592) return;
    int tsel = idx / 110592;
    int r    = idx - tsel * 110592;
    int ci   = r / 1728;
    int rr   = r - ci * 1728;
    int k27  = rr >> 6;
    int o    = rr & 63;
    int p    = k27 / 9, tap = k27 - p * 9;
    const float* src = tsel ? ow : bw;
    ws[(tsel ? WTOO : WTBO) + r] = src[o * 1728 + (p * 64 + ci) * 9 + tap];
}

// Fused top+center 1x1 SelfONN convs as GEMM; writes bf16 TRANSPOSED [n][p].
__global__ __launch_bounds__(256) void k_conv1(const float* __restrict__ x,
                                               const float* __restrict__ tw, const float* __restrict__ tb,
                                               const float* __restrict__ cw, const float* __restrict__ cb,
                                               short* __restrict__ topd, short* __restrict__ cend) {
    __shared__ float xt[4096];        // [ci][n] raw x tile
    __shared__ float wtc[64 * 68];    // [ci][o] weight chunk (one power), padded
    int t  = threadIdx.x;
    int bx = blockIdx.x;
    int nt = bx & 255, ot = bx >> 8;
    int b  = nt >> 6, n0 = (nt & 63) << 6;
    const float* w    = ot ? cw : tw;
    const float* bias = ot ? cb : tb;
    short* dst = (ot ? cend : topd) + b * IMG;   // IMG shorts per batch
    int tx = t & 15, ty = t >> 4;

    for (int i = t; i < 4096; i += 256) {
        int ci = i >> 6, n = i & 63;
        xt[i] = x[b * IMG + ci * 4096 + n0 + n];
    }
    float acc[4][4] = {};
    #pragma unroll
    for (int p = 0; p < 3; ++p) {
        __syncthreads();
        for (int i = t; i < 4096; i += 256) {
            int o = i >> 6, cc = i & 63;
            wtc[cc * 68 + o] = w[o * 192 + p * 64 + cc];
        }
        __syncthreads();
        #pragma unroll 4
        for (int ci = 0; ci < 64; ++ci) {
            float4 a = *(float4*)&wtc[ci * 68 + ty * 4];
            float4 v = *(float4*)&xt[ci * 64 + tx * 4];
            float vx = v.x, vy = v.y, vz = v.z, vw = v.w;
            if (p == 1) { vx *= vx; vy *= vy; vz *= vz; vw *= vw; }
            if (p == 2) { vx = vx * vx * vx; vy = vy * vy * vy; vz = vz * vz * vz; vw = vw * vw * vw; }
            acc[0][0] += a.x * vx; acc[0][1] += a.x * vy; acc[0][2] += a.x * vz; acc[0][3] += a.x * vw;
            acc[1][0] += a.y * vx; acc[1][1] += a.y * vy; acc[1][2] += a.y * vz; acc[1][3] += a.y * vw;
            acc[2][0] += a.z * vx; acc[2][1] += a.z * vy; acc[2][2] += a.z * vz; acc[2][3] += a.z * vw;
            acc[3][0] += a.w * vx; acc[3][1] += a.w * vy; acc[3][2] += a.w * vz; acc[3][3] += a.w * vw;
        }
    }
    float b0 = bias[ty * 4 + 0], b1 = bias[ty * 4 + 1], b2 = bias[ty * 4 + 2], b3 = bias[ty * 4 + 3];
    #pragma unroll
    for (int j = 0; j < 4; ++j) {
        int n = n0 + tx * 4 + j;
        short4 pk;
        pk.x = f2bf(acc[0][j] + b0);
        pk.y = f2bf(acc[1][j] + b1);
        pk.z = f2bf(acc[2][j] + b2);
        pk.w = f2bf(acc[3][j] + b3);
        *(short4*)&dst[n * 64 + ty * 4] = pk;
    }
}

// 3x3 SelfONN conv, implicit GEMM over (ci, power, tap). One block per (b, output row).
// dsth!=nullptr -> bf16 channel-major [b][o][m]; else fp32 [b][o][h][w].
__global__ __launch_bounds__(512) void k_conv3(const float* __restrict__ src,
                                               const float* __restrict__ wt,
                                               const float* __restrict__ bias,
                                               float* __restrict__ dstf, short* __restrict__ dsth) {
    __shared__ float xp[3 * 198];   // [p][kh][cc 0..65], cc = iw+1
    __shared__ float wtile[1728];   // [k27][o]
    int t  = threadIdx.x;
    int bx = blockIdx.x;
    int b  = bx >> 6, h = bx & 63;
    int tx = t & 15, ty = t >> 4;
    int w0 = tx * 4, o0 = ty * 2;
    float acc[4][2] = {};

    for (int ci = 0; ci < 64; ++ci) {
        __syncthreads();
        if (t < 198) {
            int rr = t / 66, cc = t - rr * 66;
            int ih = h + rr - 1, iw = cc - 1;
            float xv = 0.f;
            if (ih >= 0 && ih < 64 && iw >= 0 && iw < 64)
                xv = src[b * IMG + ci * 4096 + ih * 64 + iw];
            xp[rr * 66 + cc]       = xv;
            xp[198 + rr * 66 + cc] = xv * xv;
            xp[396 + rr * 66 + cc] = xv * xv * xv;
        }
        for (int i = t; i < 1728; i += 512)
            wtile[i] = wt[ci * 1728 + i];
        __syncthreads();
        #pragma unroll
        for (int p = 0; p < 3; ++p) {
            #pragma unroll
            for (int kh = 0; kh < 3; ++kh) {
                float xv[6];
                #pragma unroll
                for (int q = 0; q < 6; ++q) xv[q] = xp[p * 198 + kh * 66 + w0 + q];
                #pragma unroll
                for (int kw = 0; kw < 3; ++kw) {
                    int k27 = p * 9 + kh * 3 + kw;
                    float2 wv = *(float2*)&wtile[k27 * 64 + o0];
                    #pragma unroll
                    for (int j = 0; j < 4; ++j) {
                        acc[j][0] += wv.x * xv[j + kw];
                        acc[j][1] += wv.y * xv[j + kw];
                    }
                }
            }
        }
    }
    if (dsth) {
        #pragma unroll
        for (int i2 = 0; i2 < 2; ++i2) {
            int o = o0 + i2;
            float bv = bias[o];
            short4 pk;
            pk.x = f2bf(acc[0][i2] + bv);
            pk.y = f2bf(acc[1][i2] + bv);
            pk.z = f2bf(acc[2][i2] + bv);
            pk.w = f2bf(acc[3][i2] + bv);
            *(short4*)&dsth[b * IMG + o * 4096 + h * 64 + w0] = pk;
        }
    } else {
        #pragma unroll
        for (int i2 = 0; i2 < 2; ++i2) {
            int o = o0 + i2;
            float bv = bias[o];
            float4 r = make_float4(acc[0][i2] + bv, acc[1][i2] + bv, acc[2][i2] + bv, acc[3][i2] + bv);
            *(float4*)&dstf[b * IMG + o * 4096 + h * 64 + w0] = r;
        }
    }
}

// bf16 MFMA flash attention with global softmax. grid 512: (strip 32) x (b 4) x (split 4).
// Block: 128-row n-strip, 4 waves x 32 rows; iterates 16 m-tiles of 64.
__global__ __launch_bounds__(256, 2) void k_attn(float* __restrict__ ws) {
    __shared__ short ltop[64 * 72];   // [m][p] B-operand tile for S
    __shared__ short lbot[64 * 72];   // [c][m] B-operand tile for PV
    __shared__ short lp[128 * 72];    // [n][m] P tile (A-operand for PV)
    __shared__ float red[4], zred[4];
    int t    = threadIdx.x;
    int lane = t & 63, w = t >> 6;
    int l16  = lane & 15, quad = lane >> 4;
    int bx = blockIdx.x;
    int st = bx & 31, b = (bx >> 5) & 3, s = bx >> 7;
    int n0 = st * 128;
    const short* topg = (const short*)(ws + TOPO) + b * IMG;
    const short* ceng = (const short*)(ws + CENO) + b * IMG;
    const short* botg = (const short*)(ws + BOTO) + b * IMG;

    // Preload center A-fragments (fixed per block): A[i=n][k=p]
    short8v afr[2][2];
    #pragma unroll
    for (int i = 0; i < 2; ++i)
        #pragma unroll
        for (int kk = 0; kk < 2; ++kk)
            afr[i][kk] = *(const short8v*)&ceng[(n0 + w * 32 + i * 16 + l16) * 64 + kk * 32 + quad * 8];

    f32x4 pv[2][4];
    #pragma unroll
    for (int i = 0; i < 2; ++i)
        #pragma unroll
        for (int j = 0; j < 4; ++j)
            pv[i][j] = (f32x4){0.f, 0.f, 0.f, 0.f};
    float runm = -3.0e38f, zacc = 0.f;

    for (int tt = 0; tt < 16; ++tt) {
        int m0 = s * 1024 + tt * 64;
        __syncthreads();   // prev-iter PV reads of lbot/lp done
        #pragma unroll
        for (int v = 0; v < 2; ++v) {
            int s2 = t + v * 256;              // 0..511
            int r = s2 >> 3, off = (s2 & 7) * 8;
            *(short8v*)&ltop[r * 72 + off] = *(const short8v*)&topg[(m0 + r) * 64 + off];
            *(short8v*)&lbot[r * 72 + off] = *(const short8v*)&botg[r * 4096 + m0 + off];
        }
        __syncthreads();
        // S = cen^T * top  (16 MFMAs/wave)
        f32x4 sa[2][4];
        #pragma unroll
        for (int i = 0; i < 2; ++i)
            #pragma unroll
            for (int j = 0; j < 4; ++j)
                sa[i][j] = (f32x4){0.f, 0.f, 0.f, 0.f};
        #pragma unroll
        for (int kk = 0; kk < 2; ++kk) {
            #pragma unroll
            for (int j = 0; j < 4; ++j) {
                short8v bfr = *(short8v*)&ltop[(j * 16 + l16) * 72 + kk * 32 + quad * 8];
                sa[0][j] = __builtin_amdgcn_mfma_f32_16x16x32_bf16(afr[0][kk], bfr, sa[0][j], 0, 0, 0);
                sa[1][j] = __builtin_amdgcn_mfma_f32_16x16x32_bf16(afr[1][kk], bfr, sa[1][j], 0, 0, 0);
            }
        }
        // tile max (over the whole 128x64 block tile -> scalar, global-softmax style)
        float tm = -3.0e38f;
        #pragma unroll
        for (int i = 0; i < 2; ++i)
            #pragma unroll
            for (int j = 0; j < 4; ++j)
                #pragma unroll
                for (int r = 0; r < 4; ++r) tm = fmaxf(tm, sa[i][j][r]);
        for (int off = 32; off; off >>= 1) tm = fmaxf(tm, __shfl_xor(tm, off, 64));
        if (lane == 0) red[w] = tm;
        __syncthreads();
        float tmax = fmaxf(fmaxf(red[0], red[1]), fmaxf(red[2], red[3]));
        float newm = fmaxf(runm, tmax);
        float sc = __expf(runm - newm);
        zacc *= sc;
        #pragma unroll
        for (int i = 0; i < 2; ++i)
            #pragma unroll
            for (int j = 0; j < 4; ++j)
                pv[i][j] *= sc;
        // exp + write P tile [n][m] as bf16 (A-operand layout source)
        #pragma unroll
        for (int i = 0; i < 2; ++i)
            #pragma unroll
            for (int j = 0; j < 4; ++j) {
                #pragma unroll
                for (int r = 0; r < 4; ++r) {
                    float e = __expf(sa[i][j][r] - newm);
                    zacc += e;
                    lp[(w * 32 + i * 16 + quad * 4 + r) * 72 + j * 16 + l16] = f2bf(e);
                }
            }
        runm = newm;
        __syncthreads();
        // PV += P * bot  (16 MFMAs/wave)
        #pragma unroll
        for (int kk = 0; kk < 2; ++kk) {
            short8v pa0 = *(short8v*)&lp[(w * 32 + 0  + l16) * 72 + kk * 32 + quad * 8];
            short8v pa1 = *(short8v*)&lp[(w * 32 + 16 + l16) * 72 + kk * 32 + quad * 8];
            #pragma unroll
            for (int j = 0; j < 4; ++j) {
                short8v bb = *(short8v*)&lbot[(j * 16 + l16) * 72 + kk * 32 + quad * 8];
                pv[0][j] = __builtin_amdgcn_mfma_f32_16x16x32_bf16(pa0, bb, pv[0][j], 0, 0, 0);
                pv[1][j] = __builtin_amdgcn_mfma_f32_16x16x32_bf16(pa1, bb, pv[1][j], 0, 0, 0);
            }
        }
    }
    // reduce z across block
    for (int off = 32; off; off >>= 1) zacc += __shfl_xor(zacc, off, 64);
    __syncthreads();
    if (lane == 0) zred[w] = zacc;
    __syncthreads();
    if (t == 0) {
        ws[MSO + s * 128 + b * 32 + st] = runm;
        ws[ZSO + s * 128 + b * 32 + st] = zred[0] + zred[1] + zred[2] + zred[3];
    }
    // store PV (fp32, C-layout scatter: 16-float contiguous runs per quad)
    float* pvp = ws + PVO + s * 1048576 + b * IMG;
    #pragma unroll
    for (int i = 0; i < 2; ++i)
        #pragma unroll
        for (int j = 0; j < 4; ++j)
            #pragma unroll
            for (int r = 0; r < 4; ++r)
                pvp[(n0 + w * 32 + i * 16 + quad * 4 + r) * 64 + j * 16 + l16] = pv[i][j][r];
}

// Combine per-block (m_s, Z_s) -> global M, Z per batch. 128 partials per b.
__global__ __launch_bounds__(128) void k_mz(float* __restrict__ ws) {
    int b = blockIdx.x, t = threadIdx.x;
    int idx = MSO + (t >> 5) * 128 + b * 32 + (t & 31);
    float m0 = ws[idx];
    float z0 = ws[idx + 512];   // ZSO = MSO + 512
    float m = m0;
    for (int off = 32; off; off >>= 1) m = fmaxf(m, __shfl_xor(m, off, 64));
    __shared__ float rm[2], rz[2];
    if ((t & 63) == 0) rm[t >> 6] = m;
    __syncthreads();
    float M = fmaxf(rm[0], rm[1]);
    float z = z0 * __expf(m0 - M);
    for (int off = 32; off; off >>= 1) z += __shfl_xor(z, off, 64);
    if ((t & 63) == 0) rz[t >> 6] = z;
    __syncthreads();
    if (t == 0) { ws[MO_ + b] = M; ws[ZO_ + b] = rz[0] + rz[1]; }
}

// u = x + softmax(sp) @ bottom (flat reinterpretation handles the reshape quirk)
__global__ __launch_bounds__(256) void k_finalu(const float* __restrict__ x, float* __restrict__ ws) {
    int idx = blockIdx.x * 256 + threadIdx.x;   // < 1048576
    int b = idx >> 18;
    int rem = idx & 262143;
    int strip = rem >> 13;        // n/128
    float M = ws[MO_ + b], Z = ws[ZO_ + b];
    float acc = 0.f;
    #pragma unroll
    for (int s = 0; s < MS; ++s) {
        float scl = __expf(ws[MSO + s * 128 + b * 32 + strip] - M);
        acc += ws[PVO + s * 1048576 + b * IMG + rem] * scl;
    }
    ws[UO + idx] = x[idx] + acc / Z;   // UO aliases dead top/cen region
}

extern "C" void kernel_launch(void* const* d_in, const int* in_sizes, int n_in,
                              void* d_out, int out_size, void* d_ws, size_t ws_size,
                              hipStream_t stream) {
    (void)in_sizes; (void)n_in; (void)out_size; (void)ws_size;
    const float* x  = (const float*)d_in[0];
    const float* tw = (const float*)d_in[1];
    const float* tb = (const float*)d_in[2];
    const float* cw = (const float*)d_in[3];
    const float* cb = (const float*)d_in[4];
    const float* bw = (const float*)d_in[5];
    const float* bb = (const float*)d_in[6];
    const float* ow = (const float*)d_in[7];
    const float* ob = (const float*)d_in[8];
    float* ws  = (float*)d_ws;
    float* out = (float*)d_out;

    hipLaunchKernelGGL(k_reorder, dim3(864), dim3(256), 0, stream, bw, ow, ws);
    hipLaunchKernelGGL(k_conv1, dim3(512), dim3(256), 0, stream, x, tw, tb, cw, cb,
                       (short*)(ws + TOPO), (short*)(ws + CENO));
    hipLaunchKernelGGL(k_conv3, dim3(256), dim3(512), 0, stream, x, ws + WTBO, bb,
                       (float*)nullptr, (short*)(ws + BOTO));
    hipLaunchKernelGGL(k_attn, dim3(512), dim3(256), 0, stream, ws);
    hipLaunchKernelGGL(k_mz, dim3(4), dim3(128), 0, stream, ws);
    hipLaunchKernelGGL(k_finalu, dim3(4096), dim3(256), 0, stream, x, ws);
    hipLaunchKernelGGL(k_conv3, dim3(256), dim3(512), 0, stream, ws + UO, ws + WTOO, ob,
                       out, (short*)nullptr);
}

// Round 4
// 235.022 us; speedup vs baseline: 2.8860x; 2.0968x over previous
//
#include <hip/hip_runtime.h>
#include <hip/hip_bf16.h>

// Problem constants: B=4, C=64, H=W=64, HW=4096, P=64, Q=3 (CQ=192)
namespace {
constexpr int IMG    = 262144;   // 64*4096 elems per batch image
constexpr int MS     = 4;        // attention m-split
constexpr int PADIMG = 4356;     // 66*66 padded pixels
// workspace float offsets
constexpr int WBFO  = 0;         // fp16 weights: wbot[9][64][192], wout[9][64][192], wtop[64][192], wcen[64][192]
                                 //   = 110592+110592+12288+12288 = 245760 halfs = 122880 f
constexpr int XPADO = 122880;    // fp16 xp/up padded [4][4356][192] = 3345408 halfs = 1672704 f (aliased: xp then up)
constexpr int TOPO  = 1795584;   // fp16 topT [b][m][p] = 1048576 halfs = 524288 f
constexpr int CENO  = 2319872;   // fp16 cenT [b][n][p]
constexpr int BOTO  = 2844160;   // fp16 bot  [b][c][m]
constexpr int PVO   = 3368448;   // bf16 PV [4][b][n][c] = 4194304 shorts = 2097152 f ; aliased as fp32 partials [2][16384][64]
constexpr int MSO   = 5465600;   // m_s [s 4][b 4][strip 32]
constexpr int ZSO   = 5466112;   // z_s  (MSO + 512)
constexpr int MO_   = 5466624;   // M[b]
constexpr int ZO_   = 5466628;   // Z[b]
// total = 5466632 f = 20.85 MB
}

using half8v = __attribute__((ext_vector_type(8))) _Float16;
typedef __attribute__((ext_vector_type(4))) float f32x4;

__device__ __forceinline__ short f2bf(float f) {
    __hip_bfloat16 h = __float2bfloat16(f);
    return *reinterpret_cast<short*>(&h);
}
__device__ __forceinline__ float bf2f(short s) {
    unsigned u = ((unsigned)(unsigned short)s) << 16;
    return __uint_as_float(u);
}

// Weights -> fp16. 3x3: w[o][(p*64+ci)*9+tap] -> wT[tap][o][p*64+ci]; 1x1: [o][192] cast.
__global__ void k_reorder(const float* bw, const float* ow, const float* tw, const float* cw,
                          _Float16* wbf) {
    int idx = blockIdx.x * 256 + threadIdx.x;   // < 245760
    if (idx < 221184) {
        int tsel = idx / 110592;
        int r    = idx - tsel * 110592;
        int tap  = r / 12288;
        int rr   = r - tap * 12288;
        int o    = rr / 192;
        int i    = rr - o * 192;
        const float* src = tsel ? ow : bw;
        wbf[idx] = (_Float16)src[o * 1728 + i * 9 + tap];
    } else {
        int j = idx - 221184;
        int tsel = j / 12288;
        int rr   = j - tsel * 12288;
        wbf[idx] = (_Float16)(tsel ? cw[rr] : tw[rr]);
    }
}

// x powers -> padded pixel-major fp16 [b][(h+1)*66+(w+1)][192]. One block per (b, h-row).
__global__ __launch_bounds__(256) void k_pow(const float* __restrict__ x, _Float16* __restrict__ xpad) {
    __shared__ float xs[64 * 65];
    int t = threadIdx.x, bx = blockIdx.x;
    int b = bx >> 6, h = bx & 63;
    #pragma unroll
    for (int it = 0; it < 16; ++it) {
        int idx = it * 256 + t;
        int ci = idx >> 6, wc = idx & 63;
        xs[ci * 65 + wc] = x[b * IMG + ci * 4096 + h * 64 + wc];
    }
    __syncthreads();
    _Float16* dst = xpad + ((size_t)b * PADIMG + (h + 1) * 66 + 1) * 192;
    #pragma unroll
    for (int it = 0; it < 48; ++it) {
        int idx = it * 256 + t;
        int m = idx / 192, k = idx - m * 192;
        int p = k >> 6, ci = k & 63;
        float v = xs[ci * 65 + m];
        float pw = (p == 0) ? v : ((p == 1) ? v * v : v * v * v);
        dst[m * 192 + k] = (_Float16)pw;
    }
}

// 1x1 SelfONN convs as MFMA GEMM from xpad. grid 512 = 256 (b,h) x 2 convs.
__global__ __launch_bounds__(256, 2) void k_conv1m(const _Float16* __restrict__ xpad,
                                                   const _Float16* __restrict__ wtop,
                                                   const _Float16* __restrict__ wcen,
                                                   const float* __restrict__ tb,
                                                   const float* __restrict__ cb,
                                                   _Float16* __restrict__ topd,
                                                   _Float16* __restrict__ cend) {
    int t = threadIdx.x, lane = t & 63, w = t >> 6;
    int l16 = lane & 15, quad = lane >> 4;
    int bx = blockIdx.x;
    int ot = bx >> 8, mt = bx & 255;
    int b = mt >> 6, h = mt & 63;
    const _Float16* wt   = ot ? wcen : wtop;
    const float*    bias = ot ? cb : tb;
    _Float16*       dst  = (ot ? cend : topd) + (size_t)b * IMG;
    const _Float16* abase = xpad + ((size_t)b * PADIMG + (h + 1) * 66 + (w * 16 + l16 + 1)) * 192 + quad * 8;
    const _Float16* bbase = wt + l16 * 192 + quad * 8;
    f32x4 acc[4];
    #pragma unroll
    for (int nf = 0; nf < 4; ++nf) acc[nf] = (f32x4){0.f, 0.f, 0.f, 0.f};
    #pragma unroll
    for (int kc = 0; kc < 6; ++kc) {
        half8v afr = *(const half8v*)&abase[kc * 32];
        #pragma unroll
        for (int nf = 0; nf < 4; ++nf) {
            half8v bfr = *(const half8v*)&bbase[nf * 16 * 192 + kc * 32];
            acc[nf] = __builtin_amdgcn_mfma_f32_16x16x32_f16(afr, bfr, acc[nf], 0, 0, 0);
        }
    }
    _Float16* dp = dst + (size_t)(h * 64 + w * 16) * 64;
    #pragma unroll
    for (int nf = 0; nf < 4; ++nf) {
        float bv = bias[nf * 16 + l16];
        #pragma unroll
        for (int r = 0; r < 4; ++r)
            dp[(quad * 4 + r) * 64 + nf * 16 + l16] = (_Float16)(acc[nf][r] + bv);
    }
}

// 3x3 SelfONN conv as MFMA implicit GEMM, split-K x2, no LDS.
// grid 512 = 2 splits x 256 (b,h). Writes fp32 partials [s][b*4096+m][64].
__global__ __launch_bounds__(256, 2) void k_conv3m(const _Float16* __restrict__ src,
                                                   const _Float16* __restrict__ wt,
                                                   float* __restrict__ part) {
    int t = threadIdx.x, lane = t & 63, w = t >> 6;
    int l16 = lane & 15, quad = lane >> 4;
    int bx = blockIdx.x;
    int s = bx >> 8, mt = bx & 255;
    int b = mt >> 6, h = mt & 63;
    const _Float16* abase = src + ((size_t)b * PADIMG + (h + 1) * 66 + (w * 16 + l16 + 1)) * 192 + quad * 8;
    const _Float16* bbase = wt + l16 * 192 + quad * 8;
    f32x4 acc[4];
    #pragma unroll
    for (int nf = 0; nf < 4; ++nf) acc[nf] = (f32x4){0.f, 0.f, 0.f, 0.f};
    for (int kc = 0; kc < 3; ++kc) {
        int ks = s * 96 + kc * 32;
        #pragma unroll
        for (int tap = 0; tap < 9; ++tap) {
            int dh = tap / 3 - 1, dw = tap % 3 - 1;
            half8v afr = *(const half8v*)&abase[(dh * 66 + dw) * 192 + ks];
            #pragma unroll
            for (int nf = 0; nf < 4; ++nf) {
                half8v bfr = *(const half8v*)&bbase[(tap * 64 + nf * 16) * 192 + ks];
                acc[nf] = __builtin_amdgcn_mfma_f32_16x16x32_f16(afr, bfr, acc[nf], 0, 0, 0);
            }
        }
    }
    float* pp = part + (size_t)s * 1048576 + (size_t)(b * 4096 + h * 64 + w * 16) * 64;
    #pragma unroll
    for (int nf = 0; nf < 4; ++nf)
        #pragma unroll
        for (int r = 0; r < 4; ++r)
            pp[(quad * 4 + r) * 64 + nf * 16 + l16] = acc[nf][r];
}

// Combine split-K partials + bias, transpose [m][o] -> [o][m]. fp16 out (bottom) or fp32 out (final).
__global__ __launch_bounds__(256) void k_combine(const float* __restrict__ part,
                                                 const float* __restrict__ bias,
                                                 _Float16* __restrict__ dh_, float* __restrict__ df) {
    __shared__ float st[64 * 65];
    int t = threadIdx.x, bx = blockIdx.x;
    int b = bx >> 6, h = bx & 63;
    const float* p0 = part + (size_t)(b * 4096 + h * 64) * 64;
    const float* p1 = p0 + 1048576;
    #pragma unroll
    for (int it = 0; it < 16; ++it) {
        int idx = it * 256 + t;
        int m = idx >> 6, o = idx & 63;
        st[m * 65 + o] = p0[idx] + p1[idx];
    }
    __syncthreads();
    #pragma unroll
    for (int it = 0; it < 16; ++it) {
        int idx = it * 256 + t;
        int o = idx >> 6, m = idx & 63;
        float v = st[m * 65 + o] + bias[o];
        size_t oi = (size_t)(b * 64 + o) * 4096 + h * 64 + m;
        if (dh_) dh_[oi] = (_Float16)v; else df[oi] = v;
    }
}

// fp16 MFMA flash attention with global softmax. grid 512: (strip 32) x (b 4) x (split 4).
__global__ __launch_bounds__(256, 2) void k_attn(float* __restrict__ ws) {
    __shared__ _Float16 ltop[64 * 72];   // [m][p]
    __shared__ _Float16 lbot[64 * 72];   // [c][m]
    __shared__ _Float16 lp[128 * 72];    // [n][m]
    __shared__ float red[4], zred[4];
    int t    = threadIdx.x;
    int lane = t & 63, w = t >> 6;
    int l16  = lane & 15, quad = lane >> 4;
    int bx = blockIdx.x;
    int st = bx & 31, b = (bx >> 5) & 3, s = bx >> 7;
    int n0 = st * 128;
    const _Float16* topg = (const _Float16*)(ws + TOPO) + (size_t)b * IMG;
    const _Float16* ceng = (const _Float16*)(ws + CENO) + (size_t)b * IMG;
    const _Float16* botg = (const _Float16*)(ws + BOTO) + (size_t)b * IMG;

    half8v afr[2][2];
    #pragma unroll
    for (int i = 0; i < 2; ++i)
        #pragma unroll
        for (int kk = 0; kk < 2; ++kk)
            afr[i][kk] = *(const half8v*)&ceng[(size_t)(n0 + w * 32 + i * 16 + l16) * 64 + kk * 32 + quad * 8];

    f32x4 pv[2][4];
    #pragma unroll
    for (int i = 0; i < 2; ++i)
        #pragma unroll
        for (int j = 0; j < 4; ++j)
            pv[i][j] = (f32x4){0.f, 0.f, 0.f, 0.f};
    float runm = -3.0e38f, zacc = 0.f;

    for (int tt = 0; tt < 16; ++tt) {
        int m0 = s * 1024 + tt * 64;
        __syncthreads();
        #pragma unroll
        for (int v = 0; v < 2; ++v) {
            int s2 = t + v * 256;
            int r = s2 >> 3, off = (s2 & 7) * 8;
            *(half8v*)&ltop[r * 72 + off] = *(const half8v*)&topg[(size_t)(m0 + r) * 64 + off];
            *(half8v*)&lbot[r * 72 + off] = *(const half8v*)&botg[(size_t)r * 4096 + m0 + off];
        }
        __syncthreads();
        f32x4 sa[2][4];
        #pragma unroll
        for (int i = 0; i < 2; ++i)
            #pragma unroll
            for (int j = 0; j < 4; ++j)
                sa[i][j] = (f32x4){0.f, 0.f, 0.f, 0.f};
        #pragma unroll
        for (int kk = 0; kk < 2; ++kk) {
            #pragma unroll
            for (int j = 0; j < 4; ++j) {
                half8v bfr = *(half8v*)&ltop[(j * 16 + l16) * 72 + kk * 32 + quad * 8];
                sa[0][j] = __builtin_amdgcn_mfma_f32_16x16x32_f16(afr[0][kk], bfr, sa[0][j], 0, 0, 0);
                sa[1][j] = __builtin_amdgcn_mfma_f32_16x16x32_f16(afr[1][kk], bfr, sa[1][j], 0, 0, 0);
            }
        }
        float tm = -3.0e38f;
        #pragma unroll
        for (int i = 0; i < 2; ++i)
            #pragma unroll
            for (int j = 0; j < 4; ++j)
                #pragma unroll
                for (int r = 0; r < 4; ++r) tm = fmaxf(tm, sa[i][j][r]);
        for (int off = 32; off; off >>= 1) tm = fmaxf(tm, __shfl_xor(tm, off, 64));
        if (lane == 0) red[w] = tm;
        __syncthreads();
        float tmax = fmaxf(fmaxf(red[0], red[1]), fmaxf(red[2], red[3]));
        float newm = fmaxf(runm, tmax);
        float sc = __expf(runm - newm);
        zacc *= sc;
        #pragma unroll
        for (int i = 0; i < 2; ++i)
            #pragma unroll
            for (int j = 0; j < 4; ++j)
                pv[i][j] *= sc;
        #pragma unroll
        for (int i = 0; i < 2; ++i)
            #pragma unroll
            for (int j = 0; j < 4; ++j) {
                #pragma unroll
                for (int r = 0; r < 4; ++r) {
                    float e = __expf(sa[i][j][r] - newm);
                    zacc += e;
                    lp[(w * 32 + i * 16 + quad * 4 + r) * 72 + j * 16 + l16] = (_Float16)e;
                }
            }
        runm = newm;
        __syncthreads();
        #pragma unroll
        for (int kk = 0; kk < 2; ++kk) {
            half8v pa0 = *(half8v*)&lp[(w * 32 + 0  + l16) * 72 + kk * 32 + quad * 8];
            half8v pa1 = *(half8v*)&lp[(w * 32 + 16 + l16) * 72 + kk * 32 + quad * 8];
            #pragma unroll
            for (int j = 0; j < 4; ++j) {
                half8v bb = *(half8v*)&lbot[(j * 16 + l16) * 72 + kk * 32 + quad * 8];
                pv[0][j] = __builtin_amdgcn_mfma_f32_16x16x32_f16(pa0, bb, pv[0][j], 0, 0, 0);
                pv[1][j] = __builtin_amdgcn_mfma_f32_16x16x32_f16(pa1, bb, pv[1][j], 0, 0, 0);
            }
        }
    }
    for (int off = 32; off; off >>= 1) zacc += __shfl_xor(zacc, off, 64);
    __syncthreads();
    if (lane == 0) zred[w] = zacc;
    __syncthreads();
    if (t == 0) {
        ws[MSO + s * 128 + b * 32 + st] = runm;
        ws[ZSO + s * 128 + b * 32 + st] = zred[0] + zred[1] + zred[2] + zred[3];
    }
    short* pvp = (short*)(ws + PVO) + (size_t)s * 1048576 + (size_t)b * IMG;
    #pragma unroll
    for (int i = 0; i < 2; ++i)
        #pragma unroll
        for (int j = 0; j < 4; ++j)
            #pragma unroll
            for (int r = 0; r < 4; ++r)
                pvp[(size_t)(n0 + w * 32 + i * 16 + quad * 4 + r) * 64 + j * 16 + l16] = f2bf(pv[i][j][r]);
}

// Combine per-block (m_s, Z_s) -> global M, Z per batch.
__global__ __launch_bounds__(128) void k_mz(float* __restrict__ ws) {
    int b = blockIdx.x, t = threadIdx.x;
    int idx = MSO + (t >> 5) * 128 + b * 32 + (t & 31);
    float m0 = ws[idx];
    float z0 = ws[idx + 512];
    float m = m0;
    for (int off = 32; off; off >>= 1) m = fmaxf(m, __shfl_xor(m, off, 64));
    __shared__ float rm[2], rz[2];
    if ((t & 63) == 0) rm[t >> 6] = m;
    __syncthreads();
    float M = fmaxf(rm[0], rm[1]);
    float z = z0 * __expf(m0 - M);
    for (int off = 32; off; off >>= 1) z += __shfl_xor(z, off, 64);
    if ((t & 63) == 0) rz[t >> 6] = z;
    __syncthreads();
    if (t == 0) { ws[MO_ + b] = M; ws[ZO_ + b] = rz[0] + rz[1]; }
}

// u = x + softmax@bottom (flat add), then u-powers -> padded pixel-major fp16 (aliases xpad).
__global__ __launch_bounds__(256) void k_finalu(const float* __restrict__ x, float* __restrict__ ws,
                                                _Float16* __restrict__ upad) {
    __shared__ float us[64 * 65];
    int t = threadIdx.x, bx = blockIdx.x;
    int b = bx >> 6, h = bx & 63;
    float M = ws[MO_ + b], Z = ws[ZO_ + b];
    const short* pvb = (const short*)(ws + PVO) + (size_t)b * IMG;
    #pragma unroll
    for (int it = 0; it < 16; ++it) {
        int idx = it * 256 + t;
        int ci = idx >> 6, wc = idx & 63;
        int rem = ci * 4096 + h * 64 + wc;
        int strip = ci >> 1;   // n = ci*64+h, strip = n>>7 = ci>>1 (h<64)
        float acc = 0.f;
        #pragma unroll
        for (int s = 0; s < MS; ++s) {
            // PV split stride = 4*4096*64 = 1048576 shorts (NOT 4194304 -- round-3 bug)
            float scl = __expf(ws[MSO + s * 128 + b * 32 + strip] - M);
            acc += bf2f(pvb[(size_t)s * 1048576 + rem]) * scl;
        }
        us[ci * 65 + wc] = x[(size_t)b * IMG + rem] + acc / Z;
    }
    __syncthreads();
    _Float16* dst = upad + ((size_t)b * PADIMG + (h + 1) * 66 + 1) * 192;
    #pragma unroll
    for (int it = 0; it < 48; ++it) {
        int idx = it * 256 + t;
        int m = idx / 192, k = idx - m * 192;
        int p = k >> 6, ci = k & 63;
        float v = us[ci * 65 + m];
        float pw = (p == 0) ? v : ((p == 1) ? v * v : v * v * v);
        dst[m * 192 + k] = (_Float16)pw;
    }
}

extern "C" void kernel_launch(void* const* d_in, const int* in_sizes, int n_in,
                              void* d_out, int out_size, void* d_ws, size_t ws_size,
                              hipStream_t stream) {
    (void)in_sizes; (void)n_in; (void)out_size; (void)ws_size;
    const float* x  = (const float*)d_in[0];
    const float* tw = (const float*)d_in[1];
    const float* tb = (const float*)d_in[2];
    const float* cw = (const float*)d_in[3];
    const float* cb = (const float*)d_in[4];
    const float* bw = (const float*)d_in[5];
    const float* bb = (const float*)d_in[6];
    const float* ow = (const float*)d_in[7];
    const float* ob = (const float*)d_in[8];
    float* ws  = (float*)d_ws;
    float* out = (float*)d_out;

    _Float16* wbf  = (_Float16*)(ws + WBFO);
    _Float16* wbot = wbf;
    _Float16* wout = wbf + 110592;
    _Float16* wtop = wbf + 221184;
    _Float16* wcen = wbf + 233472;
    _Float16* xpad = (_Float16*)(ws + XPADO);   // also upad (aliased)
    _Float16* topb = (_Float16*)(ws + TOPO);
    _Float16* cenb = (_Float16*)(ws + CENO);
    _Float16* botb = (_Float16*)(ws + BOTO);
    float*    part = ws + PVO;                  // fp32 partials alias PV region

    hipMemsetAsync(xpad, 0, (size_t)3345408 * sizeof(_Float16), stream);  // zero padded borders
    hipLaunchKernelGGL(k_reorder, dim3(960), dim3(256), 0, stream, bw, ow, tw, cw, wbf);
    hipLaunchKernelGGL(k_pow, dim3(256), dim3(256), 0, stream, x, xpad);
    hipLaunchKernelGGL(k_conv1m, dim3(512), dim3(256), 0, stream, xpad, wtop, wcen, tb, cb, topb, cenb);
    hipLaunchKernelGGL(k_conv3m, dim3(512), dim3(256), 0, stream, xpad, wbot, part);
    hipLaunchKernelGGL(k_combine, dim3(256), dim3(256), 0, stream, part, bb, botb, (float*)nullptr);
    hipLaunchKernelGGL(k_attn, dim3(512), dim3(256), 0, stream, ws);
    hipLaunchKernelGGL(k_mz, dim3(4), dim3(128), 0, stream, ws);
    hipLaunchKernelGGL(k_finalu, dim3(256), dim3(256), 0, stream, x, ws, xpad);
    hipLaunchKernelGGL(k_conv3m, dim3(512), dim3(256), 0, stream, xpad, wout, part);
    hipLaunchKernelGGL(k_combine, dim3(256), dim3(256), 0, stream, part, ob, (_Float16*)nullptr, out);
}

// Round 5
// 232.404 us; speedup vs baseline: 2.9185x; 1.0113x over previous
//
#include <hip/hip_runtime.h>
#include <hip/hip_bf16.h>

// Problem constants: B=4, C=64, H=W=64, HW=4096, P=64, Q=3 (CQ=192)
namespace {
constexpr int IMG    = 262144;   // 64*4096 elems per batch image
constexpr int MS     = 4;        // attention m-split
constexpr int PADIMG = 4356;     // 66*66 padded pixels
constexpr float LOG2E = 1.44269504088896340736f;
// workspace float offsets
constexpr int WBFO  = 0;         // fp16 weights: wbot[9][64][192], wout[9][64][192], wtop[64][192], wcen[64][192]
constexpr int XPADO = 122880;    // fp16 xp/up padded [4][4356][192] = 3345408 halfs (aliased: xp then up)
constexpr int TOPO  = 1795584;   // fp16 topT [b][m][p] = 1048576 halfs
constexpr int CENO  = 2319872;   // fp16 cenT [b][n][p]
constexpr int BOTO  = 2844160;   // fp16 bot  [b][c][m]
constexpr int PVO   = 3368448;   // bf16 PV [4][b][n][c] = 4194304 shorts; aliased as fp32 partials [2][16384][64]
constexpr int MSO   = 5465600;   // m_s [s 4][b 4][group 256]  (group = 16-row n-group)
constexpr int ZSO   = 5469696;   // z_s  (MSO + 4096)
constexpr int MO_   = 5473792;   // M[b]
constexpr int ZO_   = 5473796;   // Z[b]
// total = 5473800 f = 20.9 MB
}

using half8v = __attribute__((ext_vector_type(8))) _Float16;
typedef __attribute__((ext_vector_type(4))) float f32x4;

__device__ __forceinline__ short f2bf(float f) {
    __hip_bfloat16 h = __float2bfloat16(f);
    return *reinterpret_cast<short*>(&h);
}
__device__ __forceinline__ float bf2f(short s) {
    unsigned u = ((unsigned)(unsigned short)s) << 16;
    return __uint_as_float(u);
}

// Weights -> fp16. 3x3: w[o][(p*64+ci)*9+tap] -> wT[tap][o][p*64+ci]; 1x1: [o][192] cast.
// Center weights pre-scaled by log2(e): S' = S*log2e so softmax uses exp2 (saves a mul per element).
__global__ void k_reorder(const float* bw, const float* ow, const float* tw, const float* cw,
                          _Float16* wbf) {
    int idx = blockIdx.x * 256 + threadIdx.x;   // < 245760
    if (idx >= 245760) return;
    if (idx < 221184) {
        int tsel = idx / 110592;
        int r    = idx - tsel * 110592;
        int tap  = r / 12288;
        int rr   = r - tap * 12288;
        int o    = rr / 192;
        int i    = rr - o * 192;
        const float* src = tsel ? ow : bw;
        wbf[idx] = (_Float16)src[o * 1728 + i * 9 + tap];
    } else {
        int j = idx - 221184;
        int tsel = j / 12288;
        int rr   = j - tsel * 12288;
        wbf[idx] = (_Float16)(tsel ? cw[rr] * LOG2E : tw[rr]);
    }
}

// x powers -> padded pixel-major fp16 [b][(h+1)*66+(w+1)][192]. One block per (b, h-row).
__global__ __launch_bounds__(256) void k_pow(const float* __restrict__ x, _Float16* __restrict__ xpad) {
    __shared__ float xs[64 * 65];
    int t = threadIdx.x, bx = blockIdx.x;
    int b = bx >> 6, h = bx & 63;
    #pragma unroll
    for (int it = 0; it < 16; ++it) {
        int idx = it * 256 + t;
        int ci = idx >> 6, wc = idx & 63;
        xs[ci * 65 + wc] = x[b * IMG + ci * 4096 + h * 64 + wc];
    }
    __syncthreads();
    _Float16* dst = xpad + ((size_t)b * PADIMG + (h + 1) * 66 + 1) * 192;
    #pragma unroll
    for (int it = 0; it < 48; ++it) {
        int idx = it * 256 + t;
        int m = idx / 192, k = idx - m * 192;
        int p = k >> 6, ci = k & 63;
        float v = xs[ci * 65 + m];
        float pw = (p == 0) ? v : ((p == 1) ? v * v : v * v * v);
        dst[m * 192 + k] = (_Float16)pw;
    }
}

// 1x1 SelfONN convs as MFMA GEMM from xpad. grid 512 = 256 (b,h) x 2 convs.
__global__ __launch_bounds__(256, 2) void k_conv1m(const _Float16* __restrict__ xpad,
                                                   const _Float16* __restrict__ wtop,
                                                   const _Float16* __restrict__ wcen,
                                                   const float* __restrict__ tb,
                                                   const float* __restrict__ cb,
                                                   _Float16* __restrict__ topd,
                                                   _Float16* __restrict__ cend) {
    int t = threadIdx.x, lane = t & 63, w = t >> 6;
    int l16 = lane & 15, quad = lane >> 4;
    int bx = blockIdx.x;
    int ot = bx >> 8, mt = bx & 255;
    int b = mt >> 6, h = mt & 63;
    const _Float16* wt   = ot ? wcen : wtop;
    const float*    bias = ot ? cb : tb;
    _Float16*       dst  = (ot ? cend : topd) + (size_t)b * IMG;
    const _Float16* abase = xpad + ((size_t)b * PADIMG + (h + 1) * 66 + (w * 16 + l16 + 1)) * 192 + quad * 8;
    const _Float16* bbase = wt + l16 * 192 + quad * 8;
    f32x4 acc[4];
    #pragma unroll
    for (int nf = 0; nf < 4; ++nf) acc[nf] = (f32x4){0.f, 0.f, 0.f, 0.f};
    #pragma unroll
    for (int kc = 0; kc < 6; ++kc) {
        half8v afr = *(const half8v*)&abase[kc * 32];
        #pragma unroll
        for (int nf = 0; nf < 4; ++nf) {
            half8v bfr = *(const half8v*)&bbase[nf * 16 * 192 + kc * 32];
            acc[nf] = __builtin_amdgcn_mfma_f32_16x16x32_f16(afr, bfr, acc[nf], 0, 0, 0);
        }
    }
    _Float16* dp = dst + (size_t)(h * 64 + w * 16) * 64;
    #pragma unroll
    for (int nf = 0; nf < 4; ++nf) {
        float bv = bias[nf * 16 + l16];
        if (ot) bv *= LOG2E;   // center output lives in log2e-scaled domain
        #pragma unroll
        for (int r = 0; r < 4; ++r)
            dp[(quad * 4 + r) * 64 + nf * 16 + l16] = (_Float16)(acc[nf][r] + bv);
    }
}

// 3x3 SelfONN conv as MFMA implicit GEMM, split-K x2, no LDS.
// grid 512 = 2 splits x 256 (b,h). Writes fp32 partials [s][b*4096+m][64].
__global__ __launch_bounds__(256, 2) void k_conv3m(const _Float16* __restrict__ src,
                                                   const _Float16* __restrict__ wt,
                                                   float* __restrict__ part) {
    int t = threadIdx.x, lane = t & 63, w = t >> 6;
    int l16 = lane & 15, quad = lane >> 4;
    int bx = blockIdx.x;
    int s = bx >> 8, mt = bx & 255;
    int b = mt >> 6, h = mt & 63;
    const _Float16* abase = src + ((size_t)b * PADIMG + (h + 1) * 66 + (w * 16 + l16 + 1)) * 192 + quad * 8;
    const _Float16* bbase = wt + l16 * 192 + quad * 8;
    f32x4 acc[4];
    #pragma unroll
    for (int nf = 0; nf < 4; ++nf) acc[nf] = (f32x4){0.f, 0.f, 0.f, 0.f};
    for (int kc = 0; kc < 3; ++kc) {
        int ks = s * 96 + kc * 32;
        #pragma unroll
        for (int tap = 0; tap < 9; ++tap) {
            int dh = tap / 3 - 1, dw = tap % 3 - 1;
            half8v afr = *(const half8v*)&abase[(dh * 66 + dw) * 192 + ks];
            #pragma unroll
            for (int nf = 0; nf < 4; ++nf) {
                half8v bfr = *(const half8v*)&bbase[(tap * 64 + nf * 16) * 192 + ks];
                acc[nf] = __builtin_amdgcn_mfma_f32_16x16x32_f16(afr, bfr, acc[nf], 0, 0, 0);
            }
        }
    }
    float* pp = part + (size_t)s * 1048576 + (size_t)(b * 4096 + h * 64 + w * 16) * 64;
    #pragma unroll
    for (int nf = 0; nf < 4; ++nf)
        #pragma unroll
        for (int r = 0; r < 4; ++r)
            pp[(quad * 4 + r) * 64 + nf * 16 + l16] = acc[nf][r];
}

// Combine split-K partials + bias, transpose [m][o] -> [o][m]. fp16 out (bottom) or fp32 out (final).
__global__ __launch_bounds__(256) void k_combine(const float* __restrict__ part,
                                                 const float* __restrict__ bias,
                                                 _Float16* __restrict__ dh_, float* __restrict__ df) {
    __shared__ float st[64 * 65];
    int t = threadIdx.x, bx = blockIdx.x;
    int b = bx >> 6, h = bx & 63;
    const float* p0 = part + (size_t)(b * 4096 + h * 64) * 64;
    const float* p1 = p0 + 1048576;
    #pragma unroll
    for (int it = 0; it < 16; ++it) {
        int idx = it * 256 + t;
        int m = idx >> 6, o = idx & 63;
        st[m * 65 + o] = p0[idx] + p1[idx];
    }
    __syncthreads();
    #pragma unroll
    for (int it = 0; it < 16; ++it) {
        int idx = it * 256 + t;
        int o = idx >> 6, m = idx & 63;
        float v = st[m * 65 + o] + bias[o];
        size_t oi = (size_t)(b * 64 + o) * 4096 + h * 64 + m;
        if (dh_) dh_[oi] = (_Float16)v; else df[oi] = v;
    }
}

// fp16 MFMA flash attention, global softmax, PER-WAVE online max (16 n-rows per wave).
// grid 1024: (strip 64) x (b 4) x (split 4). 4 blocks/CU.
__global__ __launch_bounds__(256, 4) void k_attn(float* __restrict__ ws) {
    __shared__ _Float16 ltop[64 * 72];   // [m][p]
    __shared__ _Float16 lbot[64 * 72];   // [c][m]
    __shared__ _Float16 lp[64 * 72];     // [n][m]; wave w owns rows w*16..w*16+15
    int t    = threadIdx.x;
    int lane = t & 63, w = t >> 6;
    int l16  = lane & 15, quad = lane >> 4;
    int bx = blockIdx.x;
    int st = bx & 63, b = (bx >> 6) & 3, s = bx >> 8;
    int n0 = st * 64;
    const _Float16* topg = (const _Float16*)(ws + TOPO) + (size_t)b * IMG;
    const _Float16* ceng = (const _Float16*)(ws + CENO) + (size_t)b * IMG;
    const _Float16* botg = (const _Float16*)(ws + BOTO) + (size_t)b * IMG;

    half8v afr[2];
    #pragma unroll
    for (int kk = 0; kk < 2; ++kk)
        afr[kk] = *(const half8v*)&ceng[(size_t)(n0 + w * 16 + l16) * 64 + kk * 32 + quad * 8];

    f32x4 pv[4];
    #pragma unroll
    for (int j = 0; j < 4; ++j) pv[j] = (f32x4){0.f, 0.f, 0.f, 0.f};
    float runm = -3.0e38f, zacc = 0.f;

    for (int tt = 0; tt < 16; ++tt) {
        int m0 = s * 1024 + tt * 64;
        __syncthreads();   // prev-iter reads of ltop/lbot done
        #pragma unroll
        for (int v = 0; v < 2; ++v) {
            int s2 = t + v * 256;
            int r = s2 >> 3, off = (s2 & 7) * 8;
            *(half8v*)&ltop[r * 72 + off] = *(const half8v*)&topg[(size_t)(m0 + r) * 64 + off];
            *(half8v*)&lbot[r * 72 + off] = *(const half8v*)&botg[(size_t)r * 4096 + m0 + off];
        }
        __syncthreads();
        // S' = cen' * top (log2e-scaled), 8 MFMAs/wave
        f32x4 sa[4];
        #pragma unroll
        for (int j = 0; j < 4; ++j) sa[j] = (f32x4){0.f, 0.f, 0.f, 0.f};
        #pragma unroll
        for (int kk = 0; kk < 2; ++kk) {
            #pragma unroll
            for (int j = 0; j < 4; ++j) {
                half8v bfr = *(half8v*)&ltop[(j * 16 + l16) * 72 + kk * 32 + quad * 8];
                sa[j] = __builtin_amdgcn_mfma_f32_16x16x32_f16(afr[kk], bfr, sa[j], 0, 0, 0);
            }
        }
        // wave-local max over this wave's 16x64 tile
        float tm = -3.0e38f;
        #pragma unroll
        for (int j = 0; j < 4; ++j)
            #pragma unroll
            for (int r = 0; r < 4; ++r) tm = fmaxf(tm, sa[j][r]);
        for (int off = 32; off; off >>= 1) tm = fmaxf(tm, __shfl_xor(tm, off, 64));
        float newm = fmaxf(runm, tm);
        if (newm > runm) {          // wave-uniform branch; skip rescale when max unchanged
            float sc = exp2f(runm - newm);
            zacc *= sc;
            #pragma unroll
            for (int j = 0; j < 4; ++j) pv[j] *= sc;
            runm = newm;
        }
        // exp2 + write P tile rows (this wave's own 16 rows)
        #pragma unroll
        for (int j = 0; j < 4; ++j) {
            #pragma unroll
            for (int r = 0; r < 4; ++r) {
                float e = exp2f(sa[j][r] - runm);
                zacc += e;
                lp[(w * 16 + quad * 4 + r) * 72 + j * 16 + l16] = (_Float16)e;
            }
        }
        __syncthreads();   // lp write->read ordering (conservative)
        // PV += P * bot, 8 MFMAs/wave
        #pragma unroll
        for (int kk = 0; kk < 2; ++kk) {
            half8v pa = *(half8v*)&lp[(w * 16 + l16) * 72 + kk * 32 + quad * 8];
            #pragma unroll
            for (int j = 0; j < 4; ++j) {
                half8v bb = *(half8v*)&lbot[(j * 16 + l16) * 72 + kk * 32 + quad * 8];
                pv[j] = __builtin_amdgcn_mfma_f32_16x16x32_f16(pa, bb, pv[j], 0, 0, 0);
            }
        }
    }
    for (int off = 32; off; off >>= 1) zacc += __shfl_xor(zacc, off, 64);
    if (lane == 0) {
        ws[MSO + s * 1024 + b * 256 + st * 4 + w] = runm;
        ws[ZSO + s * 1024 + b * 256 + st * 4 + w] = zacc;
    }
    short* pvp = (short*)(ws + PVO) + (size_t)s * 1048576 + (size_t)b * IMG;
    #pragma unroll
    for (int j = 0; j < 4; ++j)
        #pragma unroll
        for (int r = 0; r < 4; ++r)
            pvp[(size_t)(n0 + w * 16 + quad * 4 + r) * 64 + j * 16 + l16] = f2bf(pv[j][r]);
}

// Combine per-(split,16-row-group) (m_s, Z_s) -> global M, Z per batch. 1024 partials per b.
__global__ __launch_bounds__(256) void k_mz(float* __restrict__ ws) {
    int b = blockIdx.x, t = threadIdx.x;
    float mv[4];
    float m = -3.0e38f;
    #pragma unroll
    for (int s = 0; s < 4; ++s) {
        mv[s] = ws[MSO + s * 1024 + b * 256 + t];
        m = fmaxf(m, mv[s]);
    }
    for (int off = 32; off; off >>= 1) m = fmaxf(m, __shfl_xor(m, off, 64));
    __shared__ float rm[4], rz[4];
    if ((t & 63) == 0) rm[t >> 6] = m;
    __syncthreads();
    float M = fmaxf(fmaxf(rm[0], rm[1]), fmaxf(rm[2], rm[3]));
    float z = 0.f;
    #pragma unroll
    for (int s = 0; s < 4; ++s)
        z += ws[ZSO + s * 1024 + b * 256 + t] * exp2f(mv[s] - M);
    for (int off = 32; off; off >>= 1) z += __shfl_xor(z, off, 64);
    if ((t & 63) == 0) rz[t >> 6] = z;
    __syncthreads();
    if (t == 0) { ws[MO_ + b] = M; ws[ZO_ + b] = rz[0] + rz[1] + rz[2] + rz[3]; }
}

// u = x + softmax@bottom (flat add), then u-powers -> padded pixel-major fp16 (aliases xpad).
__global__ __launch_bounds__(256) void k_finalu(const float* __restrict__ x, float* __restrict__ ws,
                                                _Float16* __restrict__ upad) {
    __shared__ float us[64 * 65];
    int t = threadIdx.x, bx = blockIdx.x;
    int b = bx >> 6, h = bx & 63;
    float M = ws[MO_ + b], Z = ws[ZO_ + b];
    const short* pvb = (const short*)(ws + PVO) + (size_t)b * IMG;
    int hg = h >> 4;
    #pragma unroll
    for (int it = 0; it < 16; ++it) {
        int idx = it * 256 + t;
        int ci = idx >> 6, wc = idx & 63;
        int rem = ci * 4096 + h * 64 + wc;
        int grp = ci * 4 + hg;   // n = ci*64+h; 16-row group = n>>4
        float acc = 0.f;
        #pragma unroll
        for (int s = 0; s < MS; ++s) {
            float scl = exp2f(ws[MSO + s * 1024 + b * 256 + grp] - M);
            acc += bf2f(pvb[(size_t)s * 1048576 + rem]) * scl;
        }
        us[ci * 65 + wc] = x[(size_t)b * IMG + rem] + acc / Z;
    }
    __syncthreads();
    _Float16* dst = upad + ((size_t)b * PADIMG + (h + 1) * 66 + 1) * 192;
    #pragma unroll
    for (int it = 0; it < 48; ++it) {
        int idx = it * 256 + t;
        int m = idx / 192, k = idx - m * 192;
        int p = k >> 6, ci = k & 63;
        float v = us[ci * 65 + m];
        float pw = (p == 0) ? v : ((p == 1) ? v * v : v * v * v);
        dst[m * 192 + k] = (_Float16)pw;
    }
}

extern "C" void kernel_launch(void* const* d_in, const int* in_sizes, int n_in,
                              void* d_out, int out_size, void* d_ws, size_t ws_size,
                              hipStream_t stream) {
    (void)in_sizes; (void)n_in; (void)out_size; (void)ws_size;
    const float* x  = (const float*)d_in[0];
    const float* tw = (const float*)d_in[1];
    const float* tb = (const float*)d_in[2];
    const float* cw = (const float*)d_in[3];
    const float* cb = (const float*)d_in[4];
    const float* bw = (const float*)d_in[5];
    const float* bb = (const float*)d_in[6];
    const float* ow = (const float*)d_in[7];
    const float* ob = (const float*)d_in[8];
    float* ws  = (float*)d_ws;
    float* out = (float*)d_out;

    _Float16* wbf  = (_Float16*)(ws + WBFO);
    _Float16* wbot = wbf;
    _Float16* wout = wbf + 110592;
    _Float16* wtop = wbf + 221184;
    _Float16* wcen = wbf + 233472;
    _Float16* xpad = (_Float16*)(ws + XPADO);   // also upad (aliased)
    _Float16* topb = (_Float16*)(ws + TOPO);
    _Float16* cenb = (_Float16*)(ws + CENO);
    _Float16* botb = (_Float16*)(ws + BOTO);
    float*    part = ws + PVO;                  // fp32 partials alias PV region

    hipMemsetAsync(xpad, 0, (size_t)3345408 * sizeof(_Float16), stream);  // zero padded borders
    hipLaunchKernelGGL(k_reorder, dim3(960), dim3(256), 0, stream, bw, ow, tw, cw, wbf);
    hipLaunchKernelGGL(k_pow, dim3(256), dim3(256), 0, stream, x, xpad);
    hipLaunchKernelGGL(k_conv1m, dim3(512), dim3(256), 0, stream, xpad, wtop, wcen, tb, cb, topb, cenb);
    hipLaunchKernelGGL(k_conv3m, dim3(512), dim3(256), 0, stream, xpad, wbot, part);
    hipLaunchKernelGGL(k_combine, dim3(256), dim3(256), 0, stream, part, bb, botb, (float*)nullptr);
    hipLaunchKernelGGL(k_attn, dim3(1024), dim3(256), 0, stream, ws);
    hipLaunchKernelGGL(k_mz, dim3(4), dim3(256), 0, stream, ws);
    hipLaunchKernelGGL(k_finalu, dim3(256), dim3(256), 0, stream, x, ws, xpad);
    hipLaunchKernelGGL(k_conv3m, dim3(512), dim3(256), 0, stream, xpad, wout, part);
    hipLaunchKernelGGL(k_combine, dim3(256), dim3(256), 0, stream, part, ob, (_Float16*)nullptr, out);
}